// Round 18
// baseline (46.282 us; speedup 1.0000x reference)
//
#include <hip/hip_runtime.h>

#define Bn 8
#define Nn 2048
#define Dn 128
#define OUTn 128

typedef __attribute__((ext_vector_type(8))) short bf16x8;     // bf16 MFMA operand
typedef __attribute__((ext_vector_type(8))) unsigned short ushort8;
typedef __attribute__((ext_vector_type(4))) float f32x4;      // MFMA C/D
typedef __attribute__((ext_vector_type(4))) int int4v;
typedef __attribute__((ext_vector_type(4))) float float4v;

__device__ __forceinline__ unsigned short f2bf(float f) {
  unsigned int u = __builtin_bit_cast(unsigned int, f);
  u += 0x7FFFu + ((u >> 16) & 1u);   // round-to-nearest-even
  return (unsigned short)(u >> 16);
}

// fp32 -> OCP e4m3fn (RTN, saturating). Manual fallback if cvt builtin absent.
__device__ __forceinline__ unsigned char f2e4m3(float x) {
  unsigned char s = (unsigned char)((__builtin_bit_cast(unsigned int, x) >> 24) & 0x80u);
  float a = fabsf(x);
  if (!(a >= 0.001953125f)) return s;            // < 2^-9 -> 0
  if (a >= 448.f) return (unsigned char)(s | 0x7E);
  int ex; (void)frexpf(a, &ex); int fe = ex - 1; // a in [2^fe, 2^(fe+1))
  if (fe < -6) fe = -6;
  int mant = (int)rintf(ldexpf(a, 3 - fe));      // normals: [8,16]
  if (mant >= 16) { mant >>= 1; fe += 1; }
  if (fe > 8) return (unsigned char)(s | 0x7E);
  if (mant < 8) return (unsigned char)(s | mant);         // subnormal (fe==-6)
  return (unsigned char)(s | ((fe + 7) << 3) | (mant - 8));
}

__device__ __forceinline__ unsigned int pk4_e4m3(float f0, float f1, float f2, float f3) {
#if defined(__has_builtin)
#if __has_builtin(__builtin_amdgcn_cvt_pk_fp8_f32)
  int w01 = __builtin_amdgcn_cvt_pk_fp8_f32(f0, f1, 0, false);
  int w23 = __builtin_amdgcn_cvt_pk_fp8_f32(f2, f3, 0, false);
  return (unsigned int)(w01 & 0xFFFF) | ((unsigned int)(w23 & 0xFFFF) << 16);
#else
  return (unsigned int)f2e4m3(f0) | ((unsigned int)f2e4m3(f1) << 8) |
         ((unsigned int)f2e4m3(f2) << 16) | ((unsigned int)f2e4m3(f3) << 24);
#endif
#else
  return (unsigned int)f2e4m3(f0) | ((unsigned int)f2e4m3(f1) << 8) |
         ((unsigned int)f2e4m3(f2) << 16) | ((unsigned int)f2e4m3(f3) << 24);
#endif
}

// ---------------- prep: transpose input -> fp8 inT8; transpose W -> bf16 WT --
__global__ __launch_bounds__(256) void gcn_prep(const float* __restrict__ in,
                                                const float* __restrict__ W,
                                                unsigned char* __restrict__ inT8,
                                                unsigned short* __restrict__ WT) {
  const int tid = threadIdx.x;
  if (blockIdx.x >= 256) {
    int gid = (blockIdx.x - 256) * 256 + tid;    // 0..32767
    int j = gid >> 8, k = gid & 255;             // WT[j][k] = W[k][j]
    WT[gid] = f2bf(W[k * OUTn + j]);
    return;
  }
  const int b = blockIdx.x >> 5;
  const int n0 = (blockIdx.x & 31) * 64;
  __shared__ float ldsf[64][129];                // 33 KB
  #pragma unroll
  for (int c = 0; c < 32; ++c) {
    int e = tid + c * 256;
    int i = e >> 7, d = e & 127;
    ldsf[i][d] = in[((size_t)(b * Nn + n0 + i)) * Dn + d];
  }
  __syncthreads();
  #pragma unroll
  for (int c = 0; c < 4; ++c) {
    int ch = tid + c * 256;                      // 0..1023
    int d = ch >> 3, g = (ch & 7) * 8;
    unsigned int lo = pk4_e4m3(ldsf[g][d], ldsf[g + 1][d], ldsf[g + 2][d], ldsf[g + 3][d]);
    unsigned int hi = pk4_e4m3(ldsf[g + 4][d], ldsf[g + 5][d], ldsf[g + 6][d], ldsf[g + 7][d]);
    unsigned long long v8 = (unsigned long long)lo | ((unsigned long long)hi << 32);
    *(unsigned long long*)(inT8 + ((size_t)(b * Dn + d)) * Nn + n0 + g) = v8;
  }
}

// ---------------- main: R12 structure, B staged as fp8 (bytes/CU 1036->768) --
// 256 blocks x 512 threads (8 waves). Block = 64 rows of one batch, BK=64.
// Measured ceiling is ~12.5 B/cyc/CU of DMA-delivered bytes (R9-R17 flat
// across depth/waves/conflicts) -> reduce bytes: B tile as fp8 e4m3 (8 KB vs
// 16 KB), fed to mfma_f32_16x16x32_fp8_fp8 (A in {0,1} exact as 0x38).
// A raw int32 in LDS (unchanged); 3-buf counted vmcnt, 3 loads/wave/stage.
union SMem {
  struct {
    int A[3][64][64];                  // 48 KB (swizzled content, linear layout)
    unsigned char B8[3][128][64];      // 24 KB
  } s;                                 // 72 KB
  struct {
    unsigned short aggl[64][136];      // bf16 agg for GEMM2 A-frags
    float rowsum[64][2];
    float degs[64];
  } e;
};

#define STAGE(cur, kt) do {                                                    \
    _Pragma("unroll")                                                          \
    for (int c_ = 0; c_ < 2; ++c_) {                                           \
      const int r_ = wv * 8 + c_ * 4 + (l >> 4);                               \
      const int cg_ = (l & 15) ^ (r_ & 7);                                     \
      const int* gsrc_ = adjB + (size_t)r_ * Nn + (kt) * 64 + cg_ * 4;         \
      __builtin_amdgcn_global_load_lds(                                        \
          (const __attribute__((address_space(1))) void*)gsrc_,                \
          (__attribute__((address_space(3))) void*)(smc + (cur) * 16384 +      \
                                                   wv * 2048 + c_ * 1024),     \
          16, 0, 0);                                                           \
    }                                                                          \
    {                                                                          \
      const int d_ = wv * 16 + (l >> 2);                                       \
      const int cg_ = (l & 3) ^ (d_ & 3);                                      \
      const unsigned char* gsrc_ = inT8b + (size_t)d_ * Nn + (kt) * 64 + cg_ * 16; \
      __builtin_amdgcn_global_load_lds(                                        \
          (const __attribute__((address_space(1))) void*)gsrc_,                \
          (__attribute__((address_space(3))) void*)(smc + 49152 +              \
                                                   (cur) * 8192 + wv * 1024),  \
          16, 0, 0);                                                           \
    }                                                                          \
  } while (0)

#define COMPUTE(cur) do {                                                      \
    const char* Abase = smc + (cur) * 16384 + (rg * 16 + lr) * 256;            \
    const char* Bb8 = smc + 49152 + (cur) * 8192;                              \
    _Pragma("unroll")                                                          \
    for (int kc = 0; kc < 2; ++kc) {                                           \
      const int c0_ = kc * 8 + lg * 2;                                         \
      int4v ai0 = *(const int4v*)(Abase + ((c0_ ^ swz8) * 16));                \
      int4v ai1 = *(const int4v*)(Abase + (((c0_ + 1) ^ swz8) * 16));          \
      dsum += ai0[0] + ai0[1] + ai0[2] + ai0[3] +                              \
              ai1[0] + ai1[1] + ai1[2] + ai1[3];                               \
      unsigned int alo = (unsigned)ai0[0] * 0x38u + (unsigned)ai0[1] * 0x3800u \
                       + (unsigned)ai0[2] * 0x380000u                          \
                       + (unsigned)ai0[3] * 0x38000000u;                       \
      unsigned int ahi = (unsigned)ai1[0] * 0x38u + (unsigned)ai1[1] * 0x3800u \
                       + (unsigned)ai1[2] * 0x380000u                          \
                       + (unsigned)ai1[3] * 0x38000000u;                       \
      long af = (long)(((unsigned long long)ahi << 32) | alo);                 \
      const int o_ = kc * 32 + lg * 8;                                         \
      _Pragma("unroll")                                                        \
      for (int cf = 0; cf < 4; ++cf) {                                         \
        const int brow_ = ch * 64 + cf * 16 + lr;                              \
        const int phys_ = (((o_ >> 4) ^ (brow_ & 3)) * 16) + (o_ & 15);        \
        long bf = *(const long*)(Bb8 + (size_t)brow_ * 64 + phys_);            \
        acc[cf] = __builtin_amdgcn_mfma_f32_16x16x32_fp8_fp8(af, bf, acc[cf],  \
                                                             0, 0, 0);         \
      }                                                                        \
    }                                                                          \
  } while (0)

#define WAITBAR(N) do {                                                        \
    asm volatile("s_waitcnt vmcnt(" #N ")" ::: "memory");                      \
    __builtin_amdgcn_s_barrier();                                              \
    __builtin_amdgcn_sched_barrier(0);                                         \
  } while (0)

__global__ __launch_bounds__(512, 2) void gcn_main(
    const float* __restrict__ input_, const int* __restrict__ adj,
    const float* __restrict__ bvec, const unsigned char* __restrict__ inT8,
    const unsigned short* __restrict__ WT, float* __restrict__ out) {
  __shared__ SMem sm;
  char* smc = (char*)&sm;
  const int tid = threadIdx.x;
  const int wv = tid >> 6;                       // 0..7
  const int l = tid & 63, lr = l & 15, lg = (l >> 4) & 3;
  const int rg = wv >> 1, ch = wv & 1;           // 16 rows x 64 cols per wave

  // bijective XCD swizzle: 256 blocks (%8==0) -> XCD x gets batch x
  const int swz = (blockIdx.x & 7) * 32 + (blockIdx.x >> 3);
  const int bb = swz >> 5;
  const int row0 = (swz & 31) * 64;
  const int grow0 = bb * Nn + row0;

  const int* adjB = adj + (size_t)grow0 * Nn;
  const unsigned char* inT8b = inT8 + (size_t)bb * Dn * Nn;

  const int swz8 = lr & 7;                       // A frag-read swizzle (row&7)
  f32x4 acc[4] = {};
  int dsum = 0;

  // prologue: tiles 0,1 staged (6 loads/wave in flight)
  STAGE(0, 0);
  STAGE(1, 1);

  #pragma unroll 1
  for (int j = 0; j < 10; ++j) {
    const int kt = 3 * j;
    WAITBAR(3); STAGE(2, kt + 2); COMPUTE(0);
    WAITBAR(3); STAGE(0, kt + 3); COMPUTE(1);
    WAITBAR(3); STAGE(1, kt + 4); COMPUTE(2);
  }
  // peel kt=30 (buf0), kt=31 (buf1)
  WAITBAR(3); COMPUTE(0);
  WAITBAR(0); COMPUTE(1);

  __syncthreads();                               // close K-loop: sm re-used below

  // ---- degree (adj in {0,1}: dsum is the partial row sum; ch-waves dup) ----
  {
    int s = dsum;
    s += __shfl_xor(s, 16);
    s += __shfl_xor(s, 32);                      // lanes lr,+16,+32,+48 summed
    if (l < 16) sm.e.degs[rg * 16 + l] = (s == 0) ? 1.0f : (float)s;
  }
  __syncthreads();

  // ---- agg = acc/deg staged as bf16 for GEMM2 ----
  float dgi[4];
  #pragma unroll
  for (int reg = 0; reg < 4; ++reg)
    dgi[reg] = 1.0f / sm.e.degs[rg * 16 + lg * 4 + reg];
  #pragma unroll
  for (int cf = 0; cf < 4; ++cf)
    #pragma unroll
    for (int reg = 0; reg < 4; ++reg)
      sm.e.aggl[rg * 16 + lg * 4 + reg][ch * 64 + cf * 16 + lr] =
          f2bf(acc[cf][reg] * dgi[reg]);
  __syncthreads();

  // ---- GEMM2: [x | agg] @ W (K=256, bf16); x direct from input_, B from WT --
  f32x4 acc2[4] = {};
  const float* xrow = input_ + (size_t)(grow0 + rg * 16 + lr) * Dn;
  #pragma unroll
  for (int ks = 0; ks < 8; ++ks) {
    bf16x8 af;
    if (ks < 4) {
      float4v f0 = *(const float4v*)(xrow + ks * 32 + lg * 8);
      float4v f1 = *(const float4v*)(xrow + ks * 32 + lg * 8 + 4);
      ushort8 vv;
      #pragma unroll
      for (int e = 0; e < 4; ++e) { vv[e] = f2bf(f0[e]); vv[e + 4] = f2bf(f1[e]); }
      af = __builtin_bit_cast(bf16x8, vv);
    } else {
      af = *(const bf16x8*)&sm.e.aggl[rg * 16 + lr][(ks - 4) * 32 + lg * 8];
    }
    #pragma unroll
    for (int cf = 0; cf < 4; ++cf) {
      bf16x8 bw = *(const bf16x8*)(WT + (size_t)(ch * 64 + cf * 16 + lr) * 256 +
                                   ks * 32 + lg * 8);
      acc2[cf] = __builtin_amdgcn_mfma_f32_16x16x32_bf16(af, bw, acc2[cf], 0, 0, 0);
    }
  }

  // ---- bias + sigmoid + row L2-norm + store ----
  float bcol[4];
  #pragma unroll
  for (int cf = 0; cf < 4; ++cf) bcol[cf] = bvec[ch * 64 + cf * 16 + lr];
  float sg[4][4];
  #pragma unroll
  for (int cf = 0; cf < 4; ++cf)
    #pragma unroll
    for (int reg = 0; reg < 4; ++reg) {
      float x = acc2[cf][reg] + bcol[cf];
      sg[cf][reg] = 1.0f / (1.0f + expf(-x));
    }
  #pragma unroll
  for (int reg = 0; reg < 4; ++reg) {
    float p = 0.f;
    #pragma unroll
    for (int cf = 0; cf < 4; ++cf) p += sg[cf][reg] * sg[cf][reg];
    p += __shfl_xor(p, 1);
    p += __shfl_xor(p, 2);
    p += __shfl_xor(p, 4);
    p += __shfl_xor(p, 8);
    if (lr == 0) sm.e.rowsum[rg * 16 + lg * 4 + reg][ch] = p;
  }
  __syncthreads();
  #pragma unroll
  for (int reg = 0; reg < 4; ++reg) {
    const int row = rg * 16 + lg * 4 + reg;
    float nrm = rsqrtf(sm.e.rowsum[row][0] + sm.e.rowsum[row][1]);
    #pragma unroll
    for (int cf = 0; cf < 4; ++cf)
      out[(size_t)(grow0 + row) * OUTn + ch * 64 + cf * 16 + lr] =
          sg[cf][reg] * nrm;
  }
}

extern "C" void kernel_launch(void* const* d_in, const int* in_sizes, int n_in,
                              void* d_out, int out_size, void* d_ws, size_t ws_size,
                              hipStream_t stream) {
  (void)in_sizes; (void)n_in; (void)out_size; (void)ws_size;
  const float* input_ = (const float*)d_in[0];
  const int* adj = (const int*)d_in[1];
  const float* W = (const float*)d_in[2];
  const float* bvec = (const float*)d_in[3];
  float* out = (float*)d_out;

  unsigned char* inT8 = (unsigned char*)d_ws;                  // 2 MB (fp8)
  unsigned short* WT = (unsigned short*)((char*)d_ws + 2097152); // 64 KB bf16

  hipLaunchKernelGGL(gcn_prep, dim3(384), dim3(256), 0, stream, input_, W, inT8, WT);
  hipLaunchKernelGGL(gcn_main, dim3(256), dim3(512), 0, stream,
                     input_, adj, bvec, inT8, WT, out);
}

// Round 19
// 42.510 us; speedup vs baseline: 1.0887x; 1.0887x over previous
//
#include <hip/hip_runtime.h>

#define Bn 8
#define Nn 2048
#define Dn 128
#define OUTn 128

typedef __attribute__((ext_vector_type(8))) short bf16x8;     // MFMA A/B operand (8 bf16)
typedef __attribute__((ext_vector_type(8))) unsigned short ushort8;
typedef __attribute__((ext_vector_type(4))) float f32x4;      // MFMA C/D
typedef __attribute__((ext_vector_type(4))) int int4v;
typedef __attribute__((ext_vector_type(4))) unsigned int uint4v;
typedef __attribute__((ext_vector_type(4))) float float4v;

__device__ __forceinline__ unsigned short f2bf(float f) {
  unsigned int u = __builtin_bit_cast(unsigned int, f);
  u += 0x7FFFu + ((u >> 16) & 1u);   // round-to-nearest-even
  return (unsigned short)(u >> 16);
}

// ---------------- prep: transpose input + transpose W ----------------
__global__ __launch_bounds__(256) void gcn_prep(const float* __restrict__ in,
                                                const float* __restrict__ W,
                                                unsigned short* __restrict__ inT,
                                                unsigned short* __restrict__ WT) {
  const int tid = threadIdx.x;
  if (blockIdx.x >= 256) {
    int gid = (blockIdx.x - 256) * 256 + tid;    // 0..32767
    int j = gid >> 8, k = gid & 255;             // WT[j][k] = W[k][j]
    WT[gid] = f2bf(W[k * OUTn + j]);
    return;
  }
  const int b = blockIdx.x >> 5;
  const int n0 = (blockIdx.x & 31) * 64;
  __shared__ __attribute__((aligned(16))) unsigned short lds[64][130];
  #pragma unroll
  for (int c = 0; c < 32; ++c) {
    int e = tid + c * 256;
    int i = e >> 7, d = e & 127;
    lds[i][d] = f2bf(in[((size_t)(b * Nn + n0 + i)) * Dn + d]);
  }
  __syncthreads();
  #pragma unroll
  for (int c = 0; c < 4; ++c) {
    int ch = tid + c * 256;
    int d = ch >> 3, g = (ch & 7) * 8;
    ushort8 v;
    #pragma unroll
    for (int e = 0; e < 8; ++e) v[e] = lds[g + e][d];
    *(ushort8*)(inT + ((size_t)(b * Dn + d)) * Nn + n0 + g) = v;
  }
}

// ---------------- main: counted-vmcnt DMA, 3-buf, BM=64 (empirical optimum) --
// 256 blocks x 512 threads (8 waves). Block = 64 rows of one batch, BK=64.
// Per iter: WAITBAR(4) [tile kt landed; kt+1's 4 loads/wave in flight, never
// drained] -> STAGE(kt+2) -> COMPUTE(kt). LDS 96 KB -> 1 block/CU.
// This configuration sits at the measured per-CU DMA-delivery ceiling
// (~12.5 B/cyc/CU for the 1.0 MB/CU A+B stream); depth/waves/bytes/conflict/
// quantum/dtype ablations (R9-R18) are all flat or negative around it.
// A raw int32 in LDS, converted at frag-read (adj in {0,1}: bf16 = v*0x3F80).
// 16B-chunk XOR swizzle (chunk ^= row&7) on global source + ds_read (rule #21).
union SMem {
  struct {
    int A[3][64][64];                  // 48 KB (swizzled content, linear layout)
    unsigned short Bs[3][128][64];     // 48 KB
  } s;                                 // 96 KB -> 1 block/CU
  struct {
    unsigned short aggl[64][136];      // bf16 agg for GEMM2 A-frags
    float rowsum[64][2];
    float degs[64];
  } e;
};

#define STAGE(cur, kt) do {                                                    \
    _Pragma("unroll")                                                          \
    for (int c_ = 0; c_ < 2; ++c_) {                                           \
      const int r_ = wv * 8 + c_ * 4 + (l >> 4);                               \
      const int cg_ = (l & 15) ^ (r_ & 7);                                     \
      const int* gsrc_ = adjB + (size_t)r_ * Nn + (kt) * 64 + cg_ * 4;         \
      __builtin_amdgcn_global_load_lds(                                        \
          (const __attribute__((address_space(1))) void*)gsrc_,                \
          (__attribute__((address_space(3))) void*)(smc + (cur) * 16384 +      \
                                                   wv * 2048 + c_ * 1024),     \
          16, 0, 0);                                                           \
    }                                                                          \
    _Pragma("unroll")                                                          \
    for (int c_ = 0; c_ < 2; ++c_) {                                           \
      const int d_ = wv * 16 + c_ * 8 + (l >> 3);                              \
      const int cg_ = (l & 7) ^ (d_ & 7);                                      \
      const unsigned short* gsrc_ = inTb + (size_t)d_ * Nn + (kt) * 64 + cg_ * 8; \
      __builtin_amdgcn_global_load_lds(                                        \
          (const __attribute__((address_space(1))) void*)gsrc_,                \
          (__attribute__((address_space(3))) void*)(smc + 49152 +              \
                                                   (cur) * 16384 +             \
                                                   wv * 2048 + c_ * 1024),     \
          16, 0, 0);                                                           \
    }                                                                          \
  } while (0)

#define COMPUTE(cur) do {                                                      \
    const char* Abase = smc + (cur) * 16384 + (rg * 16 + lr) * 256;            \
    const char* Bbase = smc + 49152 + (cur) * 16384;                           \
    _Pragma("unroll")                                                          \
    for (int kc = 0; kc < 2; ++kc) {                                           \
      const int c0_ = kc * 8 + lg * 2;                                         \
      int4v ai0 = *(const int4v*)(Abase + ((c0_ ^ swz8) * 16));                \
      int4v ai1 = *(const int4v*)(Abase + (((c0_ + 1) ^ swz8) * 16));          \
      dsum += ai0[0] + ai0[1] + ai0[2] + ai0[3] +                              \
              ai1[0] + ai1[1] + ai1[2] + ai1[3];                               \
      uint4v aw;                                                               \
      aw[0] = (unsigned)ai0[0] * 0x3F80u + (unsigned)ai0[1] * 0x3F800000u;     \
      aw[1] = (unsigned)ai0[2] * 0x3F80u + (unsigned)ai0[3] * 0x3F800000u;     \
      aw[2] = (unsigned)ai1[0] * 0x3F80u + (unsigned)ai1[1] * 0x3F800000u;     \
      aw[3] = (unsigned)ai1[2] * 0x3F80u + (unsigned)ai1[3] * 0x3F800000u;     \
      bf16x8 af = __builtin_bit_cast(bf16x8, aw);                              \
      _Pragma("unroll")                                                        \
      for (int cf = 0; cf < 4; ++cf) {                                         \
        const int brow_ = ch * 64 + cf * 16 + lr;                              \
        bf16x8 bfm = *(const bf16x8*)(Bbase + (size_t)brow_ * 128 +            \
                                      (((kc * 4 + lg) ^ swz8) * 16));          \
        acc[cf] = __builtin_amdgcn_mfma_f32_16x16x32_bf16(af, bfm, acc[cf],    \
                                                          0, 0, 0);            \
      }                                                                        \
    }                                                                          \
  } while (0)

#define WAITBAR(N) do {                                                        \
    asm volatile("s_waitcnt vmcnt(" #N ")" ::: "memory");                      \
    __builtin_amdgcn_s_barrier();                                              \
    __builtin_amdgcn_sched_barrier(0);                                         \
  } while (0)

__global__ __launch_bounds__(512, 2) void gcn_main(
    const float* __restrict__ input_, const int* __restrict__ adj,
    const float* __restrict__ bvec, const unsigned short* __restrict__ inT,
    const unsigned short* __restrict__ WT, float* __restrict__ out) {
  __shared__ SMem sm;
  char* smc = (char*)&sm;
  const int tid = threadIdx.x;
  const int wv = tid >> 6;                       // 0..7
  const int l = tid & 63, lr = l & 15, lg = (l >> 4) & 3;
  const int rg = wv >> 1, ch = wv & 1;           // 16 rows x 64 cols per wave

  // bijective XCD swizzle: 256 blocks (%8==0) -> XCD x gets batch x
  const int swz = (blockIdx.x & 7) * 32 + (blockIdx.x >> 3);
  const int bb = swz >> 5;
  const int row0 = (swz & 31) * 64;
  const int grow0 = bb * Nn + row0;

  const int* adjB = adj + (size_t)grow0 * Nn;
  const unsigned short* inTb = inT + (size_t)bb * Dn * Nn;

  const int swz8 = lr & 7;                       // frag-read swizzle (row&7)
  f32x4 acc[4] = {};
  int dsum = 0;

  // prologue: tiles 0,1 staged (8 loads/wave in flight)
  STAGE(0, 0);
  STAGE(1, 1);

  #pragma unroll 1
  for (int j = 0; j < 10; ++j) {
    const int kt = 3 * j;
    WAITBAR(4); STAGE(2, kt + 2); COMPUTE(0);
    WAITBAR(4); STAGE(0, kt + 3); COMPUTE(1);
    WAITBAR(4); STAGE(1, kt + 4); COMPUTE(2);
  }
  // peel kt=30 (buf0), kt=31 (buf1); no further stages
  WAITBAR(4); COMPUTE(0);
  WAITBAR(0); COMPUTE(1);

  __syncthreads();                               // close K-loop: sm re-used below

  // ---- degree (adj in {0,1}: dsum is the partial row sum; ch-waves dup) ----
  {
    int s = dsum;
    s += __shfl_xor(s, 16);
    s += __shfl_xor(s, 32);                      // lanes lr,+16,+32,+48 summed
    if (l < 16) sm.e.degs[rg * 16 + l] = (s == 0) ? 1.0f : (float)s;
  }
  __syncthreads();

  // ---- agg = acc/deg staged as bf16 for GEMM2 ----
  float dgi[4];
  #pragma unroll
  for (int reg = 0; reg < 4; ++reg)
    dgi[reg] = 1.0f / sm.e.degs[rg * 16 + lg * 4 + reg];
  #pragma unroll
  for (int cf = 0; cf < 4; ++cf)
    #pragma unroll
    for (int reg = 0; reg < 4; ++reg)
      sm.e.aggl[rg * 16 + lg * 4 + reg][ch * 64 + cf * 16 + lr] =
          f2bf(acc[cf][reg] * dgi[reg]);
  __syncthreads();

  // ---- GEMM2: [x | agg] @ W (K=256); x direct from input_, B from WT ----
  f32x4 acc2[4] = {};
  const float* xrow = input_ + (size_t)(grow0 + rg * 16 + lr) * Dn;
  #pragma unroll
  for (int ks = 0; ks < 8; ++ks) {
    bf16x8 af;
    if (ks < 4) {
      float4v f0 = *(const float4v*)(xrow + ks * 32 + lg * 8);
      float4v f1 = *(const float4v*)(xrow + ks * 32 + lg * 8 + 4);
      ushort8 vv;
      #pragma unroll
      for (int e = 0; e < 4; ++e) { vv[e] = f2bf(f0[e]); vv[e + 4] = f2bf(f1[e]); }
      af = __builtin_bit_cast(bf16x8, vv);
    } else {
      af = *(const bf16x8*)&sm.e.aggl[rg * 16 + lr][(ks - 4) * 32 + lg * 8];
    }
    #pragma unroll
    for (int cf = 0; cf < 4; ++cf) {
      bf16x8 bw = *(const bf16x8*)(WT + (size_t)(ch * 64 + cf * 16 + lr) * 256 +
                                   ks * 32 + lg * 8);
      acc2[cf] = __builtin_amdgcn_mfma_f32_16x16x32_bf16(af, bw, acc2[cf], 0, 0, 0);
    }
  }

  // ---- bias + sigmoid + row L2-norm + store ----
  float bcol[4];
  #pragma unroll
  for (int cf = 0; cf < 4; ++cf) bcol[cf] = bvec[ch * 64 + cf * 16 + lr];
  float sg[4][4];
  #pragma unroll
  for (int cf = 0; cf < 4; ++cf)
    #pragma unroll
    for (int reg = 0; reg < 4; ++reg) {
      float x = acc2[cf][reg] + bcol[cf];
      sg[cf][reg] = 1.0f / (1.0f + expf(-x));
    }
  #pragma unroll
  for (int reg = 0; reg < 4; ++reg) {
    float p = 0.f;
    #pragma unroll
    for (int cf = 0; cf < 4; ++cf) p += sg[cf][reg] * sg[cf][reg];
    p += __shfl_xor(p, 1);
    p += __shfl_xor(p, 2);
    p += __shfl_xor(p, 4);
    p += __shfl_xor(p, 8);
    if (lr == 0) sm.e.rowsum[rg * 16 + lg * 4 + reg][ch] = p;
  }
  __syncthreads();
  #pragma unroll
  for (int reg = 0; reg < 4; ++reg) {
    const int row = rg * 16 + lg * 4 + reg;
    float nrm = rsqrtf(sm.e.rowsum[row][0] + sm.e.rowsum[row][1]);
    #pragma unroll
    for (int cf = 0; cf < 4; ++cf)
      out[(size_t)(grow0 + row) * OUTn + ch * 64 + cf * 16 + lr] =
          sg[cf][reg] * nrm;
  }
}

extern "C" void kernel_launch(void* const* d_in, const int* in_sizes, int n_in,
                              void* d_out, int out_size, void* d_ws, size_t ws_size,
                              hipStream_t stream) {
  (void)in_sizes; (void)n_in; (void)out_size; (void)ws_size;
  const float* input_ = (const float*)d_in[0];
  const int* adj = (const int*)d_in[1];
  const float* W = (const float*)d_in[2];
  const float* bvec = (const float*)d_in[3];
  float* out = (float*)d_out;

  unsigned short* inT = (unsigned short*)d_ws;                 // 4 MB
  unsigned short* WT = inT + (size_t)Bn * Dn * Nn;             // 64 KB

  hipLaunchKernelGGL(gcn_prep, dim3(384), dim3(256), 0, stream, input_, W, inT, WT);
  hipLaunchKernelGGL(gcn_main, dim3(256), dim3(512), 0, stream,
                     input_, adj, bvec, inT, WT, out);
}